// Round 9
// baseline (11570.776 us; speedup 1.0000x reference)
//
#include <hip/hip_runtime.h>
#include <math.h>

// Problem constants
#define B 128
#define T 1024
#define E 256
#define H 512

// ws layout (floats):
//   h_buf : 2 * [512][128]  (double-buffered, [unit][batch])
//   last_h: [512][128]
//   last_c: [512][128]
//   flags : 8 groups x 64 ints (one 128B slot-line per group; slots 0..31 used)
#define HBUF_OFF   0
#define LASTH_OFF  (2*65536)
#define LASTC_OFF  (3*65536)
#define FLAG_OFF   (4*65536)

// Accurate transcendentals (OCML expf/tanhf).
__device__ __forceinline__ float sigm_f(float x) {
    return 1.f / (1.f + expf(-x));
}
__device__ __forceinline__ float tanh_f(float x) {
    return tanhf(x);
}

// ---- packed f32 math via NATIVE vector ops (no inline asm -> no forced
// register pairing, no copies, no spills; R8's asm variant spilled to
// scratch: WRITE_SIZE 0.26->1.25MB). LLVM selects v_pk_fma_f32 /
// v_pk_mul_f32 from v2f32 fma/mul on gfx90a+; if it declines, it emits two
// scalar v_fma_f32 (= R4 parity, benign).
typedef float f32x2 __attribute__((ext_vector_type(2)));
__device__ __forceinline__ f32x2 vfma2(f32x2 a, f32x2 b, f32x2 c) {
    return __builtin_elementwise_fma(a, b, c);
}

// 64-lane reduce-scatter of 32 per-lane values: after this, every lane's v[0]
// holds the full 64-lane sum of value index vi=(lane>>1)&31. All indices are
// compile-time (full unroll) -> stays in registers (no scratch).
__device__ __forceinline__ void reduce32(float (&v)[32], int lane) {
#define RR(MASK, HALF)                                                 \
    {                                                                  \
        const bool hi = (lane & MASK) != 0;                            \
        _Pragma("unroll")                                              \
        for (int i = 0; i < HALF; ++i) {                               \
            const float mine   = hi ? v[i + HALF] : v[i];              \
            const float theirs = hi ? v[i] : v[i + HALF];              \
            v[i] = mine + __shfl_xor(theirs, MASK);                    \
        }                                                              \
    }
    RR(32, 16)
    RR(16, 8)
    RR(8, 4)
    RR(4, 2)
    RR(2, 1)
#undef RR
    v[0] = v[0] + __shfl_xor(v[0], 1);
}

// ---------------------------------------------------------------------------
// Persistent LSTM, whole T=1024 loop in one cooperative kernel.
// EXACT R4 structure (measured best: 8.77 ms): 256 blocks x 1024 threads,
// 16 waves = 16 units (1 unit/wave), __launch_bounds__(1024,4), 64-VGPR
// regime (weights re-fetched from L2 each step, hidden by 4 waves/SIMD),
// 4-__syncthreads per step with flag-store right after the drain-sync.
//
// R9 change vs R4: dot products pair adjacent K components with native
// float2 vector fma (compiler-selectable v_pk_fma_f32). 768 -> ~480 dot
// instructions/thread/step if selected. Pairwise summation order differs
// from the serial fmaf chain -> absmax ~1e-6 instead of 0.0.
//
// g = bid>>5 (8 batch groups of 16 rows), m = bid&31 (32 unit groups of 16).
// Per-step schedule:
//   A: x-part dots batches 0..7 (no h dep, hides exchange)
//   B: wait h(t) flags (leader wave polls LLC; LDS s_go release)
//   C: stage h(t) -> LDS; sync
//   D: h-part batches 0..7; reduce32; sgate
//   E: full dots batches 8..15; reduce32; sgate
//   F: x(t+1) prefetch to regs; sync (sgate ready); epilogue (tid<256) +
//      h sc-stores; drain-sync; tid0 flag(t+1); x(t+1) LDS write; sync
// Race-freedom: flag=k means "I finished reading h(k-1) AND my h(k) is at
// the LLC". Writers of h(t+2) run only after seeing all flags>=t+1 ->
// buffer (t&1) safe to overwrite. Protocol unchanged since R4 (proven).
__global__ __launch_bounds__(1024, 4) void lstm_persistent(
    const int* __restrict__ tokens, const float* __restrict__ emb,
    const float* __restrict__ W_ih, const float* __restrict__ b_ih,
    const float* __restrict__ W_hh, const float* __restrict__ b_hh,
    const float* __restrict__ h0, const float* __restrict__ c0,
    float* __restrict__ ws) {
    const int tid = threadIdx.x, bid = blockIdx.x;
    const int g = bid >> 5, m = bid & 31;

    float* h_buf  = ws + HBUF_OFF;
    float* last_h = ws + LASTH_OFF;
    float* last_c = ws + LASTC_OFF;
    int*   flags  = (int*)(ws + FLAG_OFF) + g * 64;   // 32 slots in one line

    __shared__ __align__(16) float xh[16 * 772];   // [b][k], row stride 772
    __shared__ float sgate[4][16][17];             // [gate][unit-local][batch]
    __shared__ int   s_L[16];                      // per-batch Lsteps
    __shared__ float s_c[256];                     // c[ul*16+b], block-owned
    __shared__ int   s_go;                         // intra-block release flag
    __shared__ float lds_pad[8192];                // 32KB pad -> LDS>80KB -> 1 block/CU

    // volatile touch: not removable by DCE (keeps the occupancy limiter)
    {
        volatile float* vp = lds_pad;
        for (int i = tid; i < 8192; i += 1024) vp[i] = 0.f;
    }
    if (tid == 0) s_go = 0;

    // ---- per-batch lengths (all 32 blocks of a group compute identical s_L/Tg)
    if (tid < 16) s_L[tid] = T;
    __syncthreads();
    {
        const int b = tid >> 6;
        const int* tb = tokens + (size_t)(g * 16 + b) * T;
        int fz = T;
        for (int p = (tid & 63); p < T; p += 64)
            if (tb[p] == 0) fz = min(fz, p);
        atomicMin(&s_L[b], fz);
    }
    __syncthreads();
    if (tid < 16) {
        const int f = s_L[tid];
        s_L[tid] = (f == 0 || f == T) ? T : f;
    }
    __syncthreads();
    int Tg = 0;
#pragma unroll
    for (int i = 0; i < 16; ++i) Tg = max(Tg, s_L[i]);

    // ---- init block-owned c tile
    if (tid < 256) {
        const int uli = tid >> 4, bi = tid & 15;
        s_c[tid] = c0[(size_t)(g * 16 + bi) * H + (m * 16 + uli)];
    }

    // ---- stage x(0)
    {
        const int b = tid >> 6, kq4 = tid & 63;
        const int tok = tokens[(size_t)(g * 16 + b) * T + 0];
        ((float4*)&xh[b * 772])[kq4] =
            ((const float4*)emb)[(size_t)tok * 64 + kq4];
    }

    // ---- wave/lane roles + weight rows (compiler re-fetches per step from
    //      L2 in the 64-VGPR regime; that is the R4 behavior we keep)
    const int lane = tid & 63;
    const int w    = tid >> 6;            // wave index = local unit
    const int unit = m * 16 + w;
    const float4* Wi4 = (const float4*)W_ih;
    const float4* Wh4 = (const float4*)W_hh;
    float4 wx[4], wh0[4], wh1[4];         // 12 f4
#pragma unroll
    for (int G = 0; G < 4; ++G) {
        wx[G]  = Wi4[((size_t)G * H + unit) * 64 + lane];
        wh0[G] = Wh4[((size_t)G * H + unit) * 128 + lane];
        wh1[G] = Wh4[((size_t)G * H + unit) * 128 + 64 + lane];
    }

    // ---- epilogue constants (used for tid<256; loads in-bounds for all)
    const int ul2 = tid >> 4, b2 = tid & 15;
    const int unit2 = m * 16 + (ul2 & 15);
    const int bg = g * 16 + b2;
    const float bi_i = b_ih[unit2],         bh_i = b_hh[unit2];
    const float bi_f = b_ih[H + unit2],     bh_f = b_hh[H + unit2];
    const float bi_g = b_ih[2 * H + unit2], bh_g = b_hh[2 * H + unit2];
    const float bi_o = b_ih[3 * H + unit2], bh_o = b_hh[3 * H + unit2];

    __syncthreads();   // x(0), s_L, s_c, s_go visible

    float v[32];

    for (int t = 0; t < Tg; ++t) {
        // ---- Phase A: x-part, batches 0..7 (no h dependency; hides exchange)
#pragma unroll
        for (int bb = 0; bb < 8; ++bb) {
            const float4 x = ((const float4*)&xh[bb * 772])[lane];
            const f32x2 x01 = {x.x, x.y}, x23 = {x.z, x.w};
#pragma unroll
            for (int G = 0; G < 4; ++G) {
                f32x2 tacc = (f32x2){wx[G].x, wx[G].y} * x01;
                tacc = vfma2((f32x2){wx[G].z, wx[G].w}, x23, tacc);
                v[G * 8 + bb] = tacc.x + tacc.y;
            }
        }

        // ---- Phase B: wait for h(t) (leader wave polls LLC; LDS release)
        if (t > 0) {
            if (tid < 64) {
                const int* slot = &flags[tid & 31];
                while (true) {
                    const int fv = __hip_atomic_load(slot, __ATOMIC_RELAXED,
                                                     __HIP_MEMORY_SCOPE_AGENT);
                    if (__all(fv >= t)) break;
                    __builtin_amdgcn_s_sleep(1);
                }
                if (tid == 0)
                    __hip_atomic_store(&s_go, t, __ATOMIC_RELAXED,
                                       __HIP_MEMORY_SCOPE_WORKGROUP);
            } else {
                while (__hip_atomic_load(&s_go, __ATOMIC_RELAXED,
                                         __HIP_MEMORY_SCOPE_WORKGROUP) < t)
                    __builtin_amdgcn_s_sleep(1);
            }
        }

        // ---- Phase C: stage h(t) into xh[b][256+u]
        if (t == 0) {
            const int b = tid >> 6, l = tid & 63;
            const float4* h04 = (const float4*)(h0 + (size_t)(g * 16 + b) * H);
            float4* dst = (float4*)&xh[b * 772 + 256];
            dst[l]      = h04[l];
            dst[64 + l] = h04[64 + l];
        } else {
            // coherent 8B loads from LLC (bypass L1/L2; no cache maintenance)
            const unsigned long long* hs8 = (const unsigned long long*)
                (h_buf + (size_t)(t & 1) * (H * B));
            float2 hv[4];
#pragma unroll
            for (int j = 0; j < 4; ++j) {
                const int idx = j * 1024 + tid;        // [0,4096)
                const int u = idx >> 3, bp = idx & 7;
                unsigned long long val = __hip_atomic_load(
                    &hs8[(size_t)u * 64 + g * 8 + bp],
                    __ATOMIC_RELAXED, __HIP_MEMORY_SCOPE_AGENT);
                hv[j] = __builtin_bit_cast(float2, val);
            }
#pragma unroll
            for (int j = 0; j < 4; ++j) {
                const int idx = j * 1024 + tid;
                const int u = idx >> 3, bp = idx & 7;
                xh[(2 * bp) * 772 + 256 + u]     = hv[j].x;
                xh[(2 * bp + 1) * 772 + 256 + u] = hv[j].y;
            }
        }
        __syncthreads();   // sync 1/4

        // ---- Phase D: h-part batches 0..7; reduce; sgate
#pragma unroll
        for (int bb = 0; bb < 8; ++bb) {
            const float4 ha = ((const float4*)&xh[bb * 772])[64 + lane];
            const float4 hb = ((const float4*)&xh[bb * 772])[128 + lane];
            const f32x2 ha01 = {ha.x, ha.y}, ha23 = {ha.z, ha.w};
            const f32x2 hb01 = {hb.x, hb.y}, hb23 = {hb.z, hb.w};
#pragma unroll
            for (int G = 0; G < 4; ++G) {
                f32x2 tacc = (f32x2){wh0[G].x, wh0[G].y} * ha01;
                tacc = vfma2((f32x2){wh0[G].z, wh0[G].w}, ha23, tacc);
                tacc = vfma2((f32x2){wh1[G].x, wh1[G].y}, hb01, tacc);
                tacc = vfma2((f32x2){wh1[G].z, wh1[G].w}, hb23, tacc);
                v[G * 8 + bb] = v[G * 8 + bb] + (tacc.x + tacc.y);
            }
        }
        reduce32(v, lane);
        if ((lane & 1) == 0) {
            const int vi = (lane >> 1) & 31;
            sgate[vi >> 3][w][vi & 7] = v[0];
        }

        // ---- Phase E: full dots batches 8..15; reduce; sgate
#pragma unroll
        for (int bb = 0; bb < 8; ++bb) {
            const float4 x  = ((const float4*)&xh[(8 + bb) * 772])[lane];
            const float4 ha = ((const float4*)&xh[(8 + bb) * 772])[64 + lane];
            const float4 hb = ((const float4*)&xh[(8 + bb) * 772])[128 + lane];
            const f32x2 x01 = {x.x, x.y},   x23 = {x.z, x.w};
            const f32x2 ha01 = {ha.x, ha.y}, ha23 = {ha.z, ha.w};
            const f32x2 hb01 = {hb.x, hb.y}, hb23 = {hb.z, hb.w};
#pragma unroll
            for (int G = 0; G < 4; ++G) {
                f32x2 tacc = (f32x2){wx[G].x, wx[G].y} * x01;
                tacc = vfma2((f32x2){wx[G].z, wx[G].w}, x23, tacc);
                tacc = vfma2((f32x2){wh0[G].x, wh0[G].y}, ha01, tacc);
                tacc = vfma2((f32x2){wh0[G].z, wh0[G].w}, ha23, tacc);
                tacc = vfma2((f32x2){wh1[G].x, wh1[G].y}, hb01, tacc);
                tacc = vfma2((f32x2){wh1[G].z, wh1[G].w}, hb23, tacc);
                v[G * 8 + bb] = tacc.x + tacc.y;
            }
        }
        reduce32(v, lane);
        if ((lane & 1) == 0) {
            const int vi = (lane >> 1) & 31;
            sgate[vi >> 3][w][8 + (vi & 7)] = v[0];
        }

        // ---- Phase F: x(t+1) prefetch (latency hides under epilogue)
        float4 xreg;
        const bool do_stage = (t + 1 < Tg);
        if (do_stage) {
            const int b = tid >> 6, kq4 = tid & 63;
            const int tok = tokens[(size_t)(g * 16 + b) * T + (t + 1)];
            xreg = ((const float4*)emb)[(size_t)tok * 64 + kq4];
        }
        __syncthreads();   // sync 2/4: sgate complete before epilogue reads

        // ---- epilogue: gates + elementwise (tid<256)
        if (tid < 256) {
            const float ai = sgate[0][ul2][b2] + bi_i + bh_i;
            const float af = sgate[1][ul2][b2] + bi_f + bh_f;
            const float ag = sgate[2][ul2][b2] + bi_g + bh_g;
            const float ao = sgate[3][ul2][b2] + bi_o + bh_o;

            const float ig = sigm_f(ai);
            const float fg = sigm_f(af);
            const float gv = tanh_f(ag);
            const float og = sigm_f(ao);

            const float c_old = s_c[tid];
            const float c_new = fg * c_old + ig * gv;
            const float h_new = og * tanh_f(c_new);
            s_c[tid] = c_new;

            const int idx = unit2 * B + bg;
            __hip_atomic_store(&h_buf[(size_t)((t + 1) & 1) * (H * B) + idx],
                               h_new, __ATOMIC_RELAXED,
                               __HIP_MEMORY_SCOPE_AGENT);
            if (t == s_L[b2] - 1) {
                last_h[idx] = h_new;
                last_c[idx] = c_new;
            }
        }

        // ---- handoff to step t+1 (R4 ordering: flag right after drain-sync)
        if (do_stage) {
            __syncthreads();   // sync 3/4: drains vmcnt -> h stores at LLC
            if (tid == 0)
                __hip_atomic_store(&flags[m], t + 1, __ATOMIC_RELAXED,
                                   __HIP_MEMORY_SCOPE_AGENT);
            {
                const int b = tid >> 6, kq4 = tid & 63;
                ((float4*)&xh[b * 772])[kq4] = xreg;
            }
            __syncthreads();   // sync 4/4: x(t+1) staged before next Phase A
        }
    }
}

// ---------------------------------------------------------------------------
// final: y = [h;c] @ W_proj^T + b_proj ; out = y @ W_out^T + b_out
// grid 128 x 256 (unchanged)
__global__ __launch_bounds__(256) void final_kernel(
    const float* __restrict__ ws_ro, const float* __restrict__ W_proj,
    const float* __restrict__ b_proj, const float* __restrict__ W_out,
    const float* __restrict__ b_out, float* __restrict__ out) {
    const int bg = blockIdx.x, tid = threadIdx.x;
    const float* last_h = ws_ro + LASTH_OFF;
    const float* last_c = ws_ro + LASTC_OFF;

    __shared__ __align__(16) float s_hc[2 * H];
    __shared__ float s_y[H];
    for (int u = tid; u < H; u += 256) {
        s_hc[u]     = last_h[u * B + bg];
        s_hc[H + u] = last_c[u * B + bg];
    }
    __syncthreads();

    const float4* hc4 = (const float4*)s_hc;
    const float4* Wp4 = (const float4*)W_proj;
#pragma unroll
    for (int jj = 0; jj < 2; ++jj) {
        const int j = tid + jj * 256;
        const float4* wr = Wp4 + (size_t)j * 256;
        float4 acc = {0, 0, 0, 0};
#pragma unroll 4
        for (int kq = 0; kq < 256; ++kq) {
            acc.x = fmaf(wr[kq].x, hc4[kq].x, acc.x);
            acc.y = fmaf(wr[kq].y, hc4[kq].y, acc.y);
            acc.z = fmaf(wr[kq].z, hc4[kq].z, acc.z);
            acc.w = fmaf(wr[kq].w, hc4[kq].w, acc.w);
        }
        s_y[j] = acc.x + acc.y + acc.z + acc.w + b_proj[j];
    }
    __syncthreads();

    if (tid < 64) {
        float p0 = 0.f, p1 = 0.f;
        for (int j = tid; j < H; j += 64) {
            const float y = s_y[j];
            p0 = fmaf(y, W_out[j], p0);
            p1 = fmaf(y, W_out[H + j], p1);
        }
#pragma unroll
        for (int off = 32; off; off >>= 1) {
            p0 += __shfl_down(p0, off);
            p1 += __shfl_down(p1, off);
        }
        if (tid == 0) {
            out[bg * 2 + 0] = p0 + b_out[0];
            out[bg * 2 + 1] = p1 + b_out[1];
        }
    }
}

// ---------------------------------------------------------------------------
extern "C" void kernel_launch(void* const* d_in, const int* in_sizes, int n_in,
                              void* d_out, int out_size, void* d_ws, size_t ws_size,
                              hipStream_t stream) {
    const int*   tokens = (const int*)d_in[0];
    const float* emb    = (const float*)d_in[1];
    const float* W_ih   = (const float*)d_in[2];
    const float* b_ih   = (const float*)d_in[3];
    const float* W_hh   = (const float*)d_in[4];
    const float* b_hh   = (const float*)d_in[5];
    const float* W_proj = (const float*)d_in[6];
    const float* b_proj = (const float*)d_in[7];
    const float* W_out  = (const float*)d_in[8];
    const float* b_out  = (const float*)d_in[9];
    const float* h0     = (const float*)d_in[10];
    const float* c0     = (const float*)d_in[11];
    float* out = (float*)d_out;
    float* ws  = (float*)d_ws;

    // zero the per-group flag slots (required every launch/replay)
    hipMemsetAsync((char*)d_ws + (size_t)FLAG_OFF * sizeof(float), 0,
                   8 * 64 * sizeof(int), stream);

    void* kargs[] = {(void*)&tokens, (void*)&emb, (void*)&W_ih, (void*)&b_ih,
                     (void*)&W_hh, (void*)&b_hh, (void*)&h0, (void*)&c0,
                     (void*)&ws};
    // cooperative launch: guarantees all 256 blocks co-resident (1/CU with the
    // volatile LDS pad), which the flag barrier requires.
    hipLaunchCooperativeKernel((const void*)lstm_persistent, dim3(256),
                               dim3(1024), kargs, 0, stream);

    hipLaunchKernelGGL(final_kernel, dim3(B), dim3(256), 0, stream,
                       ws, W_proj, b_proj, W_out, b_out, out);
}

// Round 11
// 8788.018 us; speedup vs baseline: 1.3167x; 1.3167x over previous
//
#include <hip/hip_runtime.h>
#include <math.h>

// Problem constants
#define B 128
#define T 1024
#define E 256
#define H 512

// ws layout (floats):
//   h_buf : 2 * [512][128]  (double-buffered, [unit][batch])
//   last_h: [512][128]
//   last_c: [512][128]
//   flags : 8 groups x 64 ints (one 128B slot-line per group; slots 0..31 used)
#define HBUF_OFF   0
#define LASTH_OFF  (2*65536)
#define LASTC_OFF  (3*65536)
#define FLAG_OFF   (4*65536)

// Accurate transcendentals (OCML expf/tanhf).
__device__ __forceinline__ float sigm_f(float x) {
    return 1.f / (1.f + expf(-x));
}
__device__ __forceinline__ float tanh_f(float x) {
    return tanhf(x);
}

// 64-lane reduce-scatter of 32 per-lane values: after this, every lane's v[0]
// holds the full 64-lane sum of value index vi=(lane>>1)&31. All indices are
// compile-time (full unroll) -> stays in registers (no scratch).
__device__ __forceinline__ void reduce32(float (&v)[32], int lane) {
#define RR(MASK, HALF)                                                 \
    {                                                                  \
        const bool hi = (lane & MASK) != 0;                            \
        _Pragma("unroll")                                              \
        for (int i = 0; i < HALF; ++i) {                               \
            const float mine   = hi ? v[i + HALF] : v[i];              \
            const float theirs = hi ? v[i] : v[i + HALF];              \
            v[i] = mine + __shfl_xor(theirs, MASK);                    \
        }                                                              \
    }
    RR(32, 16)
    RR(16, 8)
    RR(8, 4)
    RR(4, 2)
    RR(2, 1)
#undef RR
    v[0] = v[0] + __shfl_xor(v[0], 1);
}

// ---------------------------------------------------------------------------
// Persistent LSTM, whole T=1024 loop in one cooperative kernel.
// 256 blocks x 1024 threads; volatile LDS pad >80KB forces 1 block/CU.
// g = bid>>5 (8 batch groups of 16 rows), m = bid&31 (32 unit groups of 16).
//
// FINAL (R11) = exact revert to the R4 kernel: the measured best of the
// session (8774 us, absmax 0.0). Wave-per-unit decomposition; weight rows
// re-fetched from L2 each step in the 64-VGPR regime (hidden by 4 waves/
// SIMD); shfl_xor reduce-scatter for gate partials; LLC flag barrier.
// All six attempted refinements (AGPR pin, waves_per_eu, 2-units/wave,
// asm pk-FMA, native pk-FMA, 2-blocks/CU) regressed or broke correctness;
// this configuration is the empirical optimum of the structure.
//
// Per-step schedule:
//   A: x-part dots batches 0..7 (no h dep, hides exchange)
//   B: wait h(t) flags (leader wave polls LLC; LDS s_go release)
//   C: stage h(t) -> LDS; sync
//   D: h-part dots batches 0..7; reduce32; sgate
//   E: full dots batches 8..15; reduce32; sgate
//   F: x(t+1) prefetch to regs; sync (sgate ready); epilogue (tid<256) +
//      h sc-stores; drain-sync; tid0 flag(t+1); x(t+1) LDS write; sync
// Race-freedom: flag=k means "I finished reading h(k-1) AND my h(k) is at
// the LLC". Writers of h(t+2) run only after seeing all flags>=t+1, i.e.
// after every peer finished reading h(t) -> buffer (t&1) safe to overwrite.
__global__ __launch_bounds__(1024, 4) void lstm_persistent(
    const int* __restrict__ tokens, const float* __restrict__ emb,
    const float* __restrict__ W_ih, const float* __restrict__ b_ih,
    const float* __restrict__ W_hh, const float* __restrict__ b_hh,
    const float* __restrict__ h0, const float* __restrict__ c0,
    float* __restrict__ ws) {
    const int tid = threadIdx.x, bid = blockIdx.x;
    const int g = bid >> 5, m = bid & 31;

    float* h_buf  = ws + HBUF_OFF;
    float* last_h = ws + LASTH_OFF;
    float* last_c = ws + LASTC_OFF;
    int*   flags  = (int*)(ws + FLAG_OFF) + g * 64;   // 32 slots in one line

    __shared__ __align__(16) float xh[16 * 772];   // [b][k], row stride 772
    __shared__ float sgate[4][16][17];             // [gate][unit-local][batch]
    __shared__ int   s_L[16];                      // per-batch Lsteps
    __shared__ float s_c[256];                     // c[ul*16+b], block-owned
    __shared__ int   s_go;                         // intra-block release flag
    __shared__ float lds_pad[8192];                // 32KB pad -> LDS>80KB -> 1 block/CU

    // volatile touch: not removable by DCE (keeps the occupancy limiter)
    {
        volatile float* vp = lds_pad;
        for (int i = tid; i < 8192; i += 1024) vp[i] = 0.f;
    }
    if (tid == 0) s_go = 0;

    // ---- per-batch lengths (all 32 blocks of a group compute identical s_L/Tg)
    if (tid < 16) s_L[tid] = T;
    __syncthreads();
    {
        const int b = tid >> 6;
        const int* tb = tokens + (size_t)(g * 16 + b) * T;
        int fz = T;
        for (int p = (tid & 63); p < T; p += 64)
            if (tb[p] == 0) fz = min(fz, p);
        atomicMin(&s_L[b], fz);
    }
    __syncthreads();
    if (tid < 16) {
        const int f = s_L[tid];
        s_L[tid] = (f == 0 || f == T) ? T : f;
    }
    __syncthreads();
    int Tg = 0;
#pragma unroll
    for (int i = 0; i < 16; ++i) Tg = max(Tg, s_L[i]);

    // ---- init block-owned c tile
    if (tid < 256) {
        const int uli = tid >> 4, bi = tid & 15;
        s_c[tid] = c0[(size_t)(g * 16 + bi) * H + (m * 16 + uli)];
    }

    // ---- stage x(0)
    {
        const int b = tid >> 6, kq4 = tid & 63;
        const int tok = tokens[(size_t)(g * 16 + b) * T + 0];
        ((float4*)&xh[b * 772])[kq4] =
            ((const float4*)emb)[(size_t)tok * 64 + kq4];
    }

    // ---- wave/lane roles + weight rows (compiler re-fetches per step from
    //      L2 in the 64-VGPR regime; that is the R4 behavior we keep)
    const int lane = tid & 63;
    const int w    = tid >> 6;            // wave index = local unit
    const int unit = m * 16 + w;
    const float4* Wi4 = (const float4*)W_ih;
    const float4* Wh4 = (const float4*)W_hh;
    float4 wx[4], wh0[4], wh1[4];         // 12 f4
#pragma unroll
    for (int G = 0; G < 4; ++G) {
        wx[G]  = Wi4[((size_t)G * H + unit) * 64 + lane];
        wh0[G] = Wh4[((size_t)G * H + unit) * 128 + lane];
        wh1[G] = Wh4[((size_t)G * H + unit) * 128 + 64 + lane];
    }

    // ---- epilogue constants (used for tid<256; loads in-bounds for all)
    const int ul2 = tid >> 4, b2 = tid & 15;
    const int unit2 = m * 16 + (ul2 & 15);
    const int bg = g * 16 + b2;
    const float bi_i = b_ih[unit2],         bh_i = b_hh[unit2];
    const float bi_f = b_ih[H + unit2],     bh_f = b_hh[H + unit2];
    const float bi_g = b_ih[2 * H + unit2], bh_g = b_hh[2 * H + unit2];
    const float bi_o = b_ih[3 * H + unit2], bh_o = b_hh[3 * H + unit2];

    __syncthreads();   // x(0), s_L, s_c, s_go visible

    float v[32];

    for (int t = 0; t < Tg; ++t) {
        // ---- Phase A: x-part, batches 0..7 (no h dependency; hides exchange)
#pragma unroll
        for (int bb = 0; bb < 8; ++bb) {
            const float4 x = ((const float4*)&xh[bb * 772])[lane];
#pragma unroll
            for (int G = 0; G < 4; ++G) {
                float p = wx[G].x * x.x;
                p = fmaf(wx[G].y, x.y, p);
                p = fmaf(wx[G].z, x.z, p);
                p = fmaf(wx[G].w, x.w, p);
                v[G * 8 + bb] = p;
            }
        }

        // ---- Phase B: wait for h(t) (leader wave polls LLC; LDS release)
        if (t > 0) {
            if (tid < 64) {
                const int* slot = &flags[tid & 31];
                while (true) {
                    const int fv = __hip_atomic_load(slot, __ATOMIC_RELAXED,
                                                     __HIP_MEMORY_SCOPE_AGENT);
                    if (__all(fv >= t)) break;
                    __builtin_amdgcn_s_sleep(1);
                }
                if (tid == 0)
                    __hip_atomic_store(&s_go, t, __ATOMIC_RELAXED,
                                       __HIP_MEMORY_SCOPE_WORKGROUP);
            } else {
                while (__hip_atomic_load(&s_go, __ATOMIC_RELAXED,
                                         __HIP_MEMORY_SCOPE_WORKGROUP) < t)
                    __builtin_amdgcn_s_sleep(1);
            }
        }

        // ---- Phase C: stage h(t) into xh[b][256+u]
        if (t == 0) {
            const int b = tid >> 6, l = tid & 63;
            const float4* h04 = (const float4*)(h0 + (size_t)(g * 16 + b) * H);
            float4* dst = (float4*)&xh[b * 772 + 256];
            dst[l]      = h04[l];
            dst[64 + l] = h04[64 + l];
        } else {
            // coherent 8B loads from LLC (bypass L1/L2; no cache maintenance)
            const unsigned long long* hs8 = (const unsigned long long*)
                (h_buf + (size_t)(t & 1) * (H * B));
            float2 hv[4];
#pragma unroll
            for (int j = 0; j < 4; ++j) {
                const int idx = j * 1024 + tid;        // [0,4096)
                const int u = idx >> 3, bp = idx & 7;
                unsigned long long val = __hip_atomic_load(
                    &hs8[(size_t)u * 64 + g * 8 + bp],
                    __ATOMIC_RELAXED, __HIP_MEMORY_SCOPE_AGENT);
                hv[j] = __builtin_bit_cast(float2, val);
            }
#pragma unroll
            for (int j = 0; j < 4; ++j) {
                const int idx = j * 1024 + tid;
                const int u = idx >> 3, bp = idx & 7;
                xh[(2 * bp) * 772 + 256 + u]     = hv[j].x;
                xh[(2 * bp + 1) * 772 + 256 + u] = hv[j].y;
            }
        }
        __syncthreads();   // sync 1/4

        // ---- Phase D: h-part batches 0..7; reduce; sgate
#pragma unroll
        for (int bb = 0; bb < 8; ++bb) {
            const float4 ha = ((const float4*)&xh[bb * 772])[64 + lane];
            const float4 hb = ((const float4*)&xh[bb * 772])[128 + lane];
#pragma unroll
            for (int G = 0; G < 4; ++G) {
                float p = v[G * 8 + bb];
                p = fmaf(wh0[G].x, ha.x, p);
                p = fmaf(wh0[G].y, ha.y, p);
                p = fmaf(wh0[G].z, ha.z, p);
                p = fmaf(wh0[G].w, ha.w, p);
                p = fmaf(wh1[G].x, hb.x, p);
                p = fmaf(wh1[G].y, hb.y, p);
                p = fmaf(wh1[G].z, hb.z, p);
                p = fmaf(wh1[G].w, hb.w, p);
                v[G * 8 + bb] = p;
            }
        }
        reduce32(v, lane);
        if ((lane & 1) == 0) {
            const int vi = (lane >> 1) & 31;
            sgate[vi >> 3][w][vi & 7] = v[0];
        }

        // ---- Phase E: full dots batches 8..15; reduce; sgate
#pragma unroll
        for (int bb = 0; bb < 8; ++bb) {
            const float4 x  = ((const float4*)&xh[(8 + bb) * 772])[lane];
            const float4 ha = ((const float4*)&xh[(8 + bb) * 772])[64 + lane];
            const float4 hb = ((const float4*)&xh[(8 + bb) * 772])[128 + lane];
#pragma unroll
            for (int G = 0; G < 4; ++G) {
                float p = wx[G].x * x.x;
                p = fmaf(wx[G].y, x.y, p);
                p = fmaf(wx[G].z, x.z, p);
                p = fmaf(wx[G].w, x.w, p);
                p = fmaf(wh0[G].x, ha.x, p);
                p = fmaf(wh0[G].y, ha.y, p);
                p = fmaf(wh0[G].z, ha.z, p);
                p = fmaf(wh0[G].w, ha.w, p);
                p = fmaf(wh1[G].x, hb.x, p);
                p = fmaf(wh1[G].y, hb.y, p);
                p = fmaf(wh1[G].z, hb.z, p);
                p = fmaf(wh1[G].w, hb.w, p);
                v[G * 8 + bb] = p;
            }
        }
        reduce32(v, lane);
        if ((lane & 1) == 0) {
            const int vi = (lane >> 1) & 31;
            sgate[vi >> 3][w][8 + (vi & 7)] = v[0];
        }

        // ---- Phase F: x(t+1) prefetch (latency hides under epilogue)
        float4 xreg;
        const bool do_stage = (t + 1 < Tg);
        if (do_stage) {
            const int b = tid >> 6, kq4 = tid & 63;
            const int tok = tokens[(size_t)(g * 16 + b) * T + (t + 1)];
            xreg = ((const float4*)emb)[(size_t)tok * 64 + kq4];
        }
        __syncthreads();   // sync 2/4: sgate complete before epilogue reads

        // ---- epilogue: gates + elementwise (tid<256)
        if (tid < 256) {
            const float ai = sgate[0][ul2][b2] + bi_i + bh_i;
            const float af = sgate[1][ul2][b2] + bi_f + bh_f;
            const float ag = sgate[2][ul2][b2] + bi_g + bh_g;
            const float ao = sgate[3][ul2][b2] + bi_o + bh_o;

            const float ig = sigm_f(ai);
            const float fg = sigm_f(af);
            const float gv = tanh_f(ag);
            const float og = sigm_f(ao);

            const float c_old = s_c[tid];
            const float c_new = fg * c_old + ig * gv;
            const float h_new = og * tanh_f(c_new);
            s_c[tid] = c_new;

            const int idx = unit2 * B + bg;
            __hip_atomic_store(&h_buf[(size_t)((t + 1) & 1) * (H * B) + idx],
                               h_new, __ATOMIC_RELAXED,
                               __HIP_MEMORY_SCOPE_AGENT);
            if (t == s_L[b2] - 1) {
                last_h[idx] = h_new;
                last_c[idx] = c_new;
            }
        }

        // ---- handoff to step t+1 (flag right after drain-sync)
        if (do_stage) {
            __syncthreads();   // sync 3/4: drains vmcnt -> h stores at LLC
            if (tid == 0)
                __hip_atomic_store(&flags[m], t + 1, __ATOMIC_RELAXED,
                                   __HIP_MEMORY_SCOPE_AGENT);
            {
                const int b = tid >> 6, kq4 = tid & 63;
                ((float4*)&xh[b * 772])[kq4] = xreg;
            }
            __syncthreads();   // sync 4/4: x(t+1) staged before next Phase A
        }
    }
}

// ---------------------------------------------------------------------------
// final: y = [h;c] @ W_proj^T + b_proj ; out = y @ W_out^T + b_out
// grid 128 x 256 (unchanged)
__global__ __launch_bounds__(256) void final_kernel(
    const float* __restrict__ ws_ro, const float* __restrict__ W_proj,
    const float* __restrict__ b_proj, const float* __restrict__ W_out,
    const float* __restrict__ b_out, float* __restrict__ out) {
    const int bg = blockIdx.x, tid = threadIdx.x;
    const float* last_h = ws_ro + LASTH_OFF;
    const float* last_c = ws_ro + LASTC_OFF;

    __shared__ __align__(16) float s_hc[2 * H];
    __shared__ float s_y[H];
    for (int u = tid; u < H; u += 256) {
        s_hc[u]     = last_h[u * B + bg];
        s_hc[H + u] = last_c[u * B + bg];
    }
    __syncthreads();

    const float4* hc4 = (const float4*)s_hc;
    const float4* Wp4 = (const float4*)W_proj;
#pragma unroll
    for (int jj = 0; jj < 2; ++jj) {
        const int j = tid + jj * 256;
        const float4* wr = Wp4 + (size_t)j * 256;
        float4 acc = {0, 0, 0, 0};
#pragma unroll 4
        for (int kq = 0; kq < 256; ++kq) {
            acc.x = fmaf(wr[kq].x, hc4[kq].x, acc.x);
            acc.y = fmaf(wr[kq].y, hc4[kq].y, acc.y);
            acc.z = fmaf(wr[kq].z, hc4[kq].z, acc.z);
            acc.w = fmaf(wr[kq].w, hc4[kq].w, acc.w);
        }
        s_y[j] = acc.x + acc.y + acc.z + acc.w + b_proj[j];
    }
    __syncthreads();

    if (tid < 64) {
        float p0 = 0.f, p1 = 0.f;
        for (int j = tid; j < H; j += 64) {
            const float y = s_y[j];
            p0 = fmaf(y, W_out[j], p0);
            p1 = fmaf(y, W_out[H + j], p1);
        }
#pragma unroll
        for (int off = 32; off; off >>= 1) {
            p0 += __shfl_down(p0, off);
            p1 += __shfl_down(p1, off);
        }
        if (tid == 0) {
            out[bg * 2 + 0] = p0 + b_out[0];
            out[bg * 2 + 1] = p1 + b_out[1];
        }
    }
}

// ---------------------------------------------------------------------------
extern "C" void kernel_launch(void* const* d_in, const int* in_sizes, int n_in,
                              void* d_out, int out_size, void* d_ws, size_t ws_size,
                              hipStream_t stream) {
    const int*   tokens = (const int*)d_in[0];
    const float* emb    = (const float*)d_in[1];
    const float* W_ih   = (const float*)d_in[2];
    const float* b_ih   = (const float*)d_in[3];
    const float* W_hh   = (const float*)d_in[4];
    const float* b_hh   = (const float*)d_in[5];
    const float* W_proj = (const float*)d_in[6];
    const float* b_proj = (const float*)d_in[7];
    const float* W_out  = (const float*)d_in[8];
    const float* b_out  = (const float*)d_in[9];
    const float* h0     = (const float*)d_in[10];
    const float* c0     = (const float*)d_in[11];
    float* out = (float*)d_out;
    float* ws  = (float*)d_ws;

    // zero the per-group flag slots (required every launch/replay)
    hipMemsetAsync((char*)d_ws + (size_t)FLAG_OFF * sizeof(float), 0,
                   8 * 64 * sizeof(int), stream);

    void* kargs[] = {(void*)&tokens, (void*)&emb, (void*)&W_ih, (void*)&b_ih,
                     (void*)&W_hh, (void*)&b_hh, (void*)&h0, (void*)&c0,
                     (void*)&ws};
    // cooperative launch: guarantees all 256 blocks co-resident (1/CU with the
    // volatile LDS pad), which the flag barrier requires.
    hipLaunchCooperativeKernel((const void*)lstm_persistent, dim3(256),
                               dim3(1024), kargs, 0, stream);

    hipLaunchKernelGGL(final_kernel, dim3(B), dim3(256), 0, stream,
                       ws, W_proj, b_proj, W_out, b_out, out);
}